// Round 11
// baseline (285.497 us; speedup 1.0000x reference)
//
#include <hip/hip_runtime.h>
#include <hip/hip_bf16.h>
#include <stdint.h>

// Problem constants
#define BB 4
#define TT 24
#define NN 325          // sequence length per (b,t)
#define DD 512
#define NH 8
#define DKH 64          // d_k per head
#define MROWS (BB*TT*NN)   // 31200 total rows
#define BTC (BB*TT)        // 96

typedef __attribute__((ext_vector_type(4))) float f32x4;
typedef __attribute__((ext_vector_type(8))) short s16x8;
typedef __attribute__((ext_vector_type(4))) unsigned int u32x4;
typedef __attribute__((ext_vector_type(2))) unsigned int u32x2;

__device__ __forceinline__ unsigned short f2bf(float f) {
    union { float f; unsigned int u; } x; x.f = f;
    unsigned int u = x.u;
    u += 0x7fffu + ((u >> 16) & 1u);   // RNE
    return (unsigned short)(u >> 16);
}
__device__ __forceinline__ unsigned int cvt2(float a, float b) {
    unsigned int r;
    asm("v_cvt_pk_bf16_f32 %0, %1, %2" : "=v"(r) : "v"(a), "v"(b));
    return r;
}
__device__ __forceinline__ unsigned short bf1(float a) {
    return (unsigned short)cvt2(a, a);
}
__device__ __forceinline__ float bf2f(unsigned int u16) {
    union { float f; unsigned int u; } x; x.u = u16 << 16; return x.f;
}

__device__ __forceinline__ void gload16(const void* g, void* l) {
    __builtin_amdgcn_global_load_lds((const __attribute__((address_space(1))) void*)g,
                                     (__attribute__((address_space(3))) void*)l, 16, 0, 0);
}

#define MEMFENCE asm volatile("" ::: "memory")

// ---------------------------------------------------------------------------
// K0: weight prep (head-permute cols, transpose to [n][k], bf16).
// ---------------------------------------------------------------------------
__global__ void prep_kernel(const float* __restrict__ Wh, const float* __restrict__ bias,
                            const float* __restrict__ Wo,
                            unsigned short* __restrict__ WtH, unsigned short* __restrict__ WtO,
                            float* __restrict__ biasp)
{
    int idx = blockIdx.x * 256 + threadIdx.x;
    if (idx < 3*512*512) {
        int i = idx >> 18; int rem = idx & 262143;
        int cp = rem >> 9; int e = rem & 511;
        int c = ((cp & 63) << 3) | (cp >> 6);
        WtH[idx] = f2bf(Wh[(i << 18) + (e << 9) + c]);
        return;
    }
    int idx2 = idx - 3*512*512;
    if (idx2 >= 0 && idx2 < 512*512) {
        int c = idx2 >> 9; int ep = idx2 & 511;
        int row = ((ep & 63) << 3) | (ep >> 6);
        WtO[idx2] = f2bf(Wo[(row << 9) + c]);
        return;
    }
    int idx3 = idx2 - 512*512;
    if (idx3 >= 0 && idx3 < 3*512) {
        int i = idx3 >> 9; int cp = idx3 & 511;
        int c = ((cp & 63) << 3) | (cp >> 6);
        biasp[idx3] = bias[(i << 9) + c];
    }
}

// ---------------------------------------------------------------------------
// K1: FUSED cvt + projection GEMM (all 3 z, 2928 = 8*366).
// A fp32: 3 ping-pong reg sets, LOADA(kk+3) issued right AFTER the compute
// barrier (2-iteration cover ~= 2x HBM latency). In-order vmcnt retirement:
// A(kk+1) is older than B(kk), so the top-of-iter vmcnt that retires B(kk)
// also guarantees A(kk+1) is in regs -> no explicit wait before its ds_write
// (compiler inserts the precise, already-satisfied wait).
// B bf16 via global_load_lds, 2 tiles ahead. Raw s_barrier; no in-loop drain.
// Top-wait table (exact, in-order ledger): kk<=1:20, kk 2..5:12, 6:4, 7:0.
// ---------------------------------------------------------------------------
__global__ __launch_bounds__(256) void projf_gemm3(
    const float* __restrict__ A0, const float* __restrict__ A1, const float* __restrict__ A2,
    const unsigned short* __restrict__ Wt, const float* __restrict__ biasp,
    unsigned short* __restrict__ Y0, unsigned short* __restrict__ Y1, unsigned short* __restrict__ Y2)
{
    __shared__ __align__(16) unsigned short Sh[4*128*64];   // 64 KB

    int orig = blockIdx.x;
    int wg = (orig & 7) * 366 + (orig >> 3);   // bijective (2928 = 8*366)
    int z = wg / 976; int rem = wg - z * 976;
    int mtile = rem >> 2; int ntile = rem & 3;

    const float* Ap = (z == 0) ? A0 : ((z == 1) ? A1 : A2);
    unsigned short* Y = (z == 0) ? Y0 : ((z == 1) ? Y1 : Y2);
    const unsigned short* Btn = Wt + z * 512 * 512 + ntile * 128 * 512;
    const float* bias = biasp + z * 512;

    int t = threadIdx.x;
    int wid = t >> 6, lane = t & 63;
    int wm = wid >> 1, wn = wid & 1;
    int lm = lane & 15, lg = lane >> 4;

    long mbase = (long)mtile * 128;

    // A: fp32 16B-granule loads. granule G = i*256 + t; row=G>>4, col16=G&15.
    int tr = t >> 4, tc = t & 15;
    long aoffg[8];
    int awr[8];                     // u32x2 (8B) units into A half of a buffer
    #pragma unroll
    for (int i = 0; i < 8; ++i) {
        int rl = i * 16 + tr;
        long rg = mbase + rl; if (rg >= MROWS) rg = MROWS - 1;
        aoffg[i] = rg * 512 + tc * 4;
        awr[i] = rl * 16 + (((tc >> 1) ^ (rl & 7)) << 1) + (tc & 1);
    }
    // B: 16B granules, inverse-swizzled source, linear LDS dest
    int boff[4];
    #pragma unroll
    for (int r = 0; r < 4; ++r) {
        int G = ((r * 4 + wid) << 6) + lane;
        int row = G >> 3;
        int slot = (G & 7) ^ (row & 7);
        boff[r] = row * 512 + slot * 8;
    }

    f32x4 acc[4][4] = {};
    f32x4 ar[3][8];                 // 3 A reg tiles (compile-time indices)

#define LOADA(kk, S) { const int k0 = (kk) * 64;                               \
    _Pragma("unroll") for (int i = 0; i < 8; ++i)                              \
        ar[S][i] = *(const f32x4*)(Ap + aoffg[i] + k0); }
#define STAGEB(kk, b) { unsigned short* Bs_ = Sh + (b) * 16384 + 8192;         \
    const int k0 = (kk) * 64;                                                  \
    _Pragma("unroll") for (int r = 0; r < 4; ++r)                              \
        gload16(Btn + boff[r] + k0, &Bs_[(r * 4 + wid) << 9]); }
#define DSWA(S, b) { u32x2* dst_ = (u32x2*)(Sh + (b) * 16384);                 \
    _Pragma("unroll") for (int i = 0; i < 8; ++i) {                            \
        u32x2 w_; w_[0] = cvt2(ar[S][i][0], ar[S][i][1]);                      \
        w_[1] = cvt2(ar[S][i][2], ar[S][i][3]); dst_[awr[i]] = w_; } }

    // prologue
    LOADA(0, 0); MEMFENCE;
    STAGEB(0, 0); MEMFENCE;
    asm volatile("s_waitcnt vmcnt(4)" ::: "memory");     // A0 regs done (B0 flying)
    DSWA(0, 0);
    LOADA(1, 1); MEMFENCE;
    STAGEB(1, 1); MEMFENCE;
    LOADA(2, 2); MEMFENCE;

    #pragma unroll
    for (int kk = 0; kk < 8; ++kk) {
        const int b = kk & 1;
        // retire B(kk) (and transitively A(kk+1), which is older)
        if (kk <= 1)      asm volatile("s_waitcnt vmcnt(20)" ::: "memory");
        else if (kk <= 5) asm volatile("s_waitcnt vmcnt(12)" ::: "memory");
        else if (kk == 6) asm volatile("s_waitcnt vmcnt(4)"  ::: "memory");
        else              asm volatile("s_waitcnt vmcnt(0)"  ::: "memory");
        asm volatile("s_waitcnt lgkmcnt(0)" ::: "memory");   // A ds_writes visible
        __builtin_amdgcn_s_barrier();

        if (kk <= 4) { LOADA(kk + 3, (kk + 3) % 3); MEMFENCE; }   // 2-iter cover

        const unsigned short* As = Sh + b * 16384;
        const unsigned short* Bs = As + 8192;
        #pragma unroll
        for (int ks = 0; ks < 2; ++ks) {
            s16x8 afr[4], bfr[4];
            #pragma unroll
            for (int mf = 0; mf < 4; ++mf) {
                int row = wm * 64 + mf * 16 + lm;
                afr[mf] = ((const s16x8*)As)[row * 8 + ((ks * 4 + lg) ^ (row & 7))];
            }
            #pragma unroll
            for (int nf = 0; nf < 4; ++nf) {
                int row = wn * 64 + nf * 16 + lm;
                bfr[nf] = ((const s16x8*)Bs)[row * 8 + ((ks * 4 + lg) ^ (row & 7))];
            }
            #pragma unroll
            for (int mf = 0; mf < 4; ++mf)
                #pragma unroll
                for (int nf = 0; nf < 4; ++nf)
                    acc[mf][nf] = __builtin_amdgcn_mfma_f32_16x16x32_bf16(afr[mf], bfr[nf], acc[mf][nf], 0, 0, 0);
        }
        MEMFENCE;
        __builtin_amdgcn_s_barrier();           // buffer b free
        if (kk <= 5) { STAGEB(kk + 2, b); MEMFENCE; }
        if (kk <= 6) { DSWA((kk + 1) % 3, b ^ 1); }   // A(kk+1) already retired
    }
#undef LOADA
#undef STAGEB
#undef DSWA

    // ---- LDS-transpose epilogue (Sh[0..32KB) as 128x128 bf16) ----
    __syncthreads();
    #pragma unroll
    for (int nf = 0; nf < 4; ++nf) {
        int col = wn * 64 + nf * 16 + lm;
        float bv = bias[ntile * 128 + col];
        #pragma unroll
        for (int mf = 0; mf < 4; ++mf) {
            #pragma unroll
            for (int j = 0; j < 4; ++j) {
                int row = wm * 64 + mf * 16 + lg * 4 + j;
                Sh[row * 128 + (col ^ ((row & 12) << 2))] = bf1(acc[mf][nf][j] + bv);
            }
        }
    }
    __syncthreads();
    #pragma unroll
    for (int it = 0; it < 8; ++it) {
        int row = it * 16 + (t >> 4);
        int c8 = (t & 15) * 8;
        u32x4 v = *(const u32x4*)&Sh[row * 128 + (c8 ^ ((row & 12) << 2))];
        long grow = mbase + row;
        if (grow < MROWS)
            *(u32x4*)&Y[grow * 512 + ntile * 128 + c8] = v;
    }
}

// ---------------------------------------------------------------------------
// K3: out-projection + residual, counted-vmcnt pipelined GEMM.
// ---------------------------------------------------------------------------
__global__ __launch_bounds__(256) void out_gemm(
    const unsigned short* __restrict__ A, const unsigned short* __restrict__ Bt,
    const float* __restrict__ X, unsigned short* __restrict__ Out)
{
    __shared__ __align__(16) unsigned short Sh[4*128*64];

    int orig = blockIdx.x;
    int wg = (orig & 7) * 122 + (orig >> 3);
    int mtile = wg >> 2; int ntile = wg & 3;

    int t = threadIdx.x;
    int wid = t >> 6, lane = t & 63;
    int wm = wid >> 1, wn = wid & 1;
    int lm = lane & 15, lg = lane >> 4;

    long mbase = (long)mtile * 128;
    const unsigned short* Abase = A + mbase * 512;
    const unsigned short* Btn = Bt + ntile * 128 * 512;

    int aoff[4], boff[4];
    #pragma unroll
    for (int r = 0; r < 4; ++r) {
        int G = ((r * 4 + wid) << 6) + lane;
        int row = G >> 3;
        int slot = (G & 7) ^ (row & 7);
        int rowc = row;
        if (mbase + row > MROWS - 1) rowc = (int)(MROWS - 1 - mbase);
        aoff[r] = rowc * 512 + slot * 8;
        boff[r] = row * 512 + slot * 8;
    }

    f32x4 acc[4][4] = {};

    auto STAGE = [&](int kk, int b) {
        unsigned short* As = Sh + b * 16384;
        unsigned short* Bs = As + 8192;
        const int k0 = kk * 64;
        #pragma unroll
        for (int r = 0; r < 4; ++r)
            gload16(Abase + aoff[r] + k0, &As[(r * 4 + wid) << 9]);
        #pragma unroll
        for (int r = 0; r < 4; ++r)
            gload16(Btn + boff[r] + k0, &Bs[(r * 4 + wid) << 9]);
    };

    STAGE(0, 0);
    STAGE(1, 1);

    #pragma unroll
    for (int kk = 0; kk < 8; ++kk) {
        const int b = kk & 1;
        if (kk < 7) asm volatile("s_waitcnt vmcnt(8)" ::: "memory");
        else        asm volatile("s_waitcnt vmcnt(0)" ::: "memory");
        __builtin_amdgcn_s_barrier();

        const unsigned short* As = Sh + b * 16384;
        const unsigned short* Bs = As + 8192;
        #pragma unroll
        for (int ks = 0; ks < 2; ++ks) {
            s16x8 afr[4], bfr[4];
            #pragma unroll
            for (int mf = 0; mf < 4; ++mf) {
                int row = wm * 64 + mf * 16 + lm;
                afr[mf] = ((const s16x8*)As)[row * 8 + ((ks * 4 + lg) ^ (row & 7))];
            }
            #pragma unroll
            for (int nf = 0; nf < 4; ++nf) {
                int row = wn * 64 + nf * 16 + lm;
                bfr[nf] = ((const s16x8*)Bs)[row * 8 + ((ks * 4 + lg) ^ (row & 7))];
            }
            #pragma unroll
            for (int mf = 0; mf < 4; ++mf)
                #pragma unroll
                for (int nf = 0; nf < 4; ++nf)
                    acc[mf][nf] = __builtin_amdgcn_mfma_f32_16x16x32_bf16(afr[mf], bfr[nf], acc[mf][nf], 0, 0, 0);
        }
        MEMFENCE;
        __builtin_amdgcn_s_barrier();
        if (kk + 2 < 8) STAGE(kk + 2, b);
    }

    __syncthreads();
    #pragma unroll
    for (int nf = 0; nf < 4; ++nf) {
        int col = wn * 64 + nf * 16 + lm;
        #pragma unroll
        for (int mf = 0; mf < 4; ++mf) {
            #pragma unroll
            for (int j = 0; j < 4; ++j) {
                int row = wm * 64 + mf * 16 + lg * 4 + j;
                Sh[row * 128 + (col ^ ((row & 12) << 2))] = bf1(acc[mf][nf][j]);
            }
        }
    }
    __syncthreads();
    #pragma unroll
    for (int it = 0; it < 8; ++it) {
        int row = it * 16 + (t >> 4);
        int c8 = (t & 15) * 8;
        u32x4 v = *(const u32x4*)&Sh[row * 128 + (c8 ^ ((row & 12) << 2))];
        long grow = mbase + row;
        if (grow < MROWS) {
            long gidx = grow * 512 + ntile * 128 + c8;
            const float* xp = X + gidx;
            f32x4 x0 = *(const f32x4*)xp, x1 = *(const f32x4*)(xp + 4);
            float xx[8] = {x0[0], x0[1], x0[2], x0[3], x1[0], x1[1], x1[2], x1[3]};
            u32x4 o;
            #pragma unroll
            for (int q = 0; q < 4; ++q) {
                float lo = bf2f(v[q] & 0xffffu) + xx[2 * q];
                float hi = bf2f(v[q] >> 16)     + xx[2 * q + 1];
                o[q] = cvt2(lo, hi);
            }
            *(u32x4*)&Out[gidx] = o;
        }
    }
}

// ---------------------------------------------------------------------------
// K2: attention, QBLK=128, shift-free softmax (unchanged).
// ---------------------------------------------------------------------------
#define SCALE2 0.18033688f   // 0.125 * log2(e)

__global__ __launch_bounds__(256) void attn_kernel(
    const unsigned short* __restrict__ Qw, const unsigned short* __restrict__ Kw,
    const unsigned short* __restrict__ Vw, unsigned short* __restrict__ Ow)
{
    __shared__ __align__(16) unsigned short Qs[128*64];
    __shared__ __align__(16) unsigned short Ks[64*64];
    __shared__ __align__(16) unsigned short Vts[64*64];
    __shared__ __align__(16) unsigned short Ps[4][16*64];

    int bid = blockIdx.x;
    int x = bid & 7, s = bid >> 3;
    int qc = s % 3;
    int gi = s / 3;
    int g  = x + 8 * gi;
    int h  = g & 7, bt = g >> 3;

    int t = threadIdx.x;
    int wid = t >> 6, lane = t & 63, lm = lane & 15, lg = lane >> 4;

    long rowbase = (long)bt * NN;
    int colbase = h * 64;
    int q0 = qc * 128;

    {
        int i = t >> 1, half = t & 1;
        int rowc = q0 + i; if (rowc > NN - 1) rowc = NN - 1;
        const u32x4* src = (const u32x4*)(Qw + (rowbase + rowc) * 512 + colbase);
        u32x4* dst = (u32x4*)Qs;
        #pragma unroll
        for (int ss = 0; ss < 4; ++ss) {
            int slot = half * 4 + ss;
            dst[i * 8 + (slot ^ (i & 7))] = src[slot];
        }
    }
    __syncthreads();
    s16x8 aq[2][2];
    #pragma unroll
    for (int qs = 0; qs < 2; ++qs) {
        int row = qs * 64 + wid * 16 + lm;
        aq[qs][0] = ((const s16x8*)Qs)[row * 8 + ((0 + lg) ^ (row & 7))];
        aq[qs][1] = ((const s16x8*)Qs)[row * 8 + ((4 + lg) ^ (row & 7))];
    }

    f32x4 oacc[2][4] = {};
    float lsum[2][4] = {};

    for (int tile = 0; tile < 6; ++tile) {
        const int kv0 = tile * 64;
        __syncthreads();
        #pragma unroll
        for (int r = 0; r < 2; ++r) {
            int G = r * 256 + t;
            int row = G >> 3;
            int slot = (G & 7) ^ (row & 7);
            int rowg = kv0 + row; if (rowg > NN - 1) rowg = NN - 1;
            gload16(Kw + (rowbase + rowg) * 512 + colbase + slot * 8, &Ks[G * 8]);
        }
        {
            int i = t >> 2, quarter = t & 3;
            int rowc = kv0 + i; if (rowc > NN - 1) rowc = NN - 1;
            const u32x4* src = (const u32x4*)(Vw + (rowbase + rowc) * 512 + colbase + quarter * 16);
            unsigned short vb[16] __attribute__((aligned(16)));
            *((u32x4*)vb) = src[0];
            *((u32x4*)(vb + 8)) = src[1];
            #pragma unroll
            for (int e = 0; e < 16; ++e) {
                int dk = quarter * 16 + e;
                int sv = (dk & 7) ^ ((dk >> 3) & 7);
                Vts[dk * 64 + (i ^ (sv << 3))] = vb[e];
            }
        }
        asm volatile("s_waitcnt vmcnt(0)" ::: "memory");
        __syncthreads();

        const bool tail = (tile == 5);
        #pragma unroll
        for (int qs = 0; qs < 2; ++qs) {
            f32x4 sacc[4] = {};
            #pragma unroll
            for (int ks = 0; ks < 2; ++ks) {
                #pragma unroll
                for (int nf = 0; nf < 4; ++nf) {
                    int row = nf * 16 + lm;
                    s16x8 bk = ((const s16x8*)Ks)[row * 8 + ((ks*4 + lg) ^ (row & 7))];
                    sacc[nf] = __builtin_amdgcn_mfma_f32_16x16x32_bf16(aq[qs][ks], bk, sacc[nf], 0, 0, 0);
                }
            }
            #pragma unroll
            for (int nf = 0; nf < 4; ++nf) {
                bool valid = !tail || (kv0 + nf * 16 + lm < NN);
                #pragma unroll
                for (int j = 0; j < 4; ++j) {
                    float pv = valid ? exp2f(sacc[nf][j] * SCALE2) : 0.f;
                    lsum[qs][j] += pv;
                    int r = lg * 4 + j;
                    int col = nf * 16 + lm;
                    Ps[wid][r * 64 + (col ^ (((r >> 1) & 7) << 3))] = bf1(pv);
                }
            }
            #pragma unroll
            for (int ks = 0; ks < 2; ++ks) {
                s16x8 ap = ((const s16x8*)Ps[wid])[lm * 8 + ((ks*4 + lg) ^ ((lm >> 1) & 7))];
                #pragma unroll
                for (int df = 0; df < 4; ++df) {
                    int vrow = df * 16 + lm;
                    int sv = (vrow & 7) ^ ((vrow >> 3) & 7);
                    s16x8 bv = ((const s16x8*)Vts)[vrow * 8 + ((ks*4 + lg) ^ sv)];
                    oacc[qs][df] = __builtin_amdgcn_mfma_f32_16x16x32_bf16(ap, bv, oacc[qs][df], 0, 0, 0);
                }
            }
        }
    }

    #pragma unroll
    for (int qs = 0; qs < 2; ++qs) {
        float inv[4];
        #pragma unroll
        for (int j = 0; j < 4; ++j) {
            float v = lsum[qs][j];
            v += __shfl_xor(v, 1, 16);
            v += __shfl_xor(v, 2, 16);
            v += __shfl_xor(v, 4, 16);
            v += __shfl_xor(v, 8, 16);
            inv[j] = __builtin_amdgcn_rcpf(v);
        }
        #pragma unroll
        for (int df = 0; df < 4; ++df) {
            int dk = df * 16 + lm;
            #pragma unroll
            for (int j = 0; j < 4; ++j) {
                int rloc = q0 + qs * 64 + wid * 16 + lg * 4 + j;
                if (rloc < NN)
                    Ow[(rowbase + rloc) * 512 + colbase + dk] = bf1(oacc[qs][df][j] * inv[j]);
            }
        }
    }
}

// ---------------------------------------------------------------------------
// K4: LayerNorm over D=512 (bf16 input, fp32 output), one wave per row.
// ---------------------------------------------------------------------------
__global__ __launch_bounds__(256) void ln_kernel(
    const unsigned short* __restrict__ T, const float* __restrict__ gamma,
    const float* __restrict__ beta, float* __restrict__ Outp)
{
    int wid = threadIdx.x >> 6, lane = threadIdx.x & 63;
    long row = (long)blockIdx.x * 4 + wid;
    s16x8 h = ((const s16x8*)(T + row * 512))[lane];
    float v[8];
    #pragma unroll
    for (int j = 0; j < 8; ++j) v[j] = bf2f((unsigned int)(unsigned short)h[j]);
    float s = 0.f, sq = 0.f;
    #pragma unroll
    for (int j = 0; j < 8; ++j) { s += v[j]; sq += v[j] * v[j]; }
    #pragma unroll
    for (int m = 1; m < 64; m <<= 1) {
        s  += __shfl_xor(s, m);
        sq += __shfl_xor(sq, m);
    }
    float mean = s * (1.f / 512.f);
    float var = sq * (1.f / 512.f) - mean * mean;
    float rstd = rsqrtf(var + 1e-5f);
    const float4* g = (const float4*)gamma;
    const float4* b = (const float4*)beta;
    float4 g0 = g[lane * 2], g1 = g[lane * 2 + 1];
    float4 b0 = b[lane * 2], b1 = b[lane * 2 + 1];
    float4 o0, o1;
    o0.x = (v[0] - mean) * rstd * g0.x + b0.x;
    o0.y = (v[1] - mean) * rstd * g0.y + b0.y;
    o0.z = (v[2] - mean) * rstd * g0.z + b0.z;
    o0.w = (v[3] - mean) * rstd * g0.w + b0.w;
    o1.x = (v[4] - mean) * rstd * g1.x + b1.x;
    o1.y = (v[5] - mean) * rstd * g1.y + b1.y;
    o1.z = (v[6] - mean) * rstd * g1.z + b1.z;
    o1.w = (v[7] - mean) * rstd * g1.w + b1.w;
    float4* dst = (float4*)(Outp + row * 512);
    dst[lane * 2]     = o0;
    dst[lane * 2 + 1] = o1;
}

// ---------------------------------------------------------------------------
extern "C" void kernel_launch(void* const* d_in, const int* in_sizes, int n_in,
                              void* d_out, int out_size, void* d_ws, size_t ws_size,
                              hipStream_t stream)
{
    const float* X  = (const float*)d_in[0];
    const float* Q  = (const float*)d_in[1];
    const float* K  = (const float*)d_in[2];
    const float* V  = (const float*)d_in[3];
    const float* Wh = (const float*)d_in[4];
    const float* bi = (const float*)d_in[5];
    const float* Wo = (const float*)d_in[6];
    const float* gamma = (const float*)d_in[7];
    const float* beta  = (const float*)d_in[8];

    char* ws = (char*)d_ws;
    const size_t msz = (size_t)MROWS * 512 * 2;          // ~31.9 MB
    unsigned short* q_ws = (unsigned short*)(ws);
    unsigned short* k_ws = (unsigned short*)(ws + msz);
    unsigned short* v_ws = (unsigned short*)(ws + 2 * msz);
    unsigned short* o_ws = (unsigned short*)(ws + 3 * msz);
    unsigned short* WtH  = (unsigned short*)(ws + 4 * msz);
    unsigned short* WtO  = WtH + 3 * 512 * 512;
    float* biasp         = (float*)(ws + 4 * msz + (size_t)4*512*512*2);
    unsigned short* tmpb = q_ws;   // pre-LN bf16; q dead after attention

    prep_kernel<<<4102, 256, 0, stream>>>(Wh, bi, Wo, WtH, WtO, biasp);

    projf_gemm3<<<2928, 256, 0, stream>>>(Q, K, V, WtH, biasp, q_ws, k_ws, v_ws);

    attn_kernel<<<2304, 256, 0, stream>>>(q_ws, k_ws, v_ws, o_ws);

    out_gemm<<<976, 256, 0, stream>>>(o_ws, WtO, X, tmpb);

    ln_kernel<<<7800, 256, 0, stream>>>(tmpb, gamma, beta, (float*)d_out);
}

// Round 12
// 233.068 us; speedup vs baseline: 1.2250x; 1.2250x over previous
//
#include <hip/hip_runtime.h>
#include <hip/hip_bf16.h>
#include <stdint.h>

// Problem constants
#define BB 4
#define TT 24
#define NN 325          // sequence length per (b,t)
#define DD 512
#define NH 8
#define DKH 64          // d_k per head
#define MROWS (BB*TT*NN)   // 31200 total rows
#define BTC (BB*TT)        // 96

typedef __attribute__((ext_vector_type(4))) float f32x4;
typedef __attribute__((ext_vector_type(8))) short s16x8;
typedef __attribute__((ext_vector_type(4))) unsigned int u32x4;
typedef __attribute__((ext_vector_type(2))) unsigned int u32x2;

__device__ __forceinline__ unsigned short f2bf(float f) {
    union { float f; unsigned int u; } x; x.f = f;
    unsigned int u = x.u;
    u += 0x7fffu + ((u >> 16) & 1u);   // RNE
    return (unsigned short)(u >> 16);
}
__device__ __forceinline__ unsigned int cvt2(float a, float b) {
    unsigned int r;
    asm("v_cvt_pk_bf16_f32 %0, %1, %2" : "=v"(r) : "v"(a), "v"(b));
    return r;
}
__device__ __forceinline__ unsigned short bf1(float a) {
    return (unsigned short)cvt2(a, a);
}
__device__ __forceinline__ float bf2f(unsigned int u16) {
    union { float f; unsigned int u; } x; x.u = u16 << 16; return x.f;
}

__device__ __forceinline__ void gload16(const void* g, void* l) {
    __builtin_amdgcn_global_load_lds((const __attribute__((address_space(1))) void*)g,
                                     (__attribute__((address_space(3))) void*)l, 16, 0, 0);
}

#define MEMFENCE asm volatile("" ::: "memory")

// ---------------------------------------------------------------------------
// K0: weight prep (head-permute cols, transpose to [n][k], bf16).
// ---------------------------------------------------------------------------
__global__ void prep_kernel(const float* __restrict__ Wh, const float* __restrict__ bias,
                            const float* __restrict__ Wo,
                            unsigned short* __restrict__ WtH, unsigned short* __restrict__ WtO,
                            float* __restrict__ biasp)
{
    int idx = blockIdx.x * 256 + threadIdx.x;
    if (idx < 3*512*512) {
        int i = idx >> 18; int rem = idx & 262143;
        int cp = rem >> 9; int e = rem & 511;
        int c = ((cp & 63) << 3) | (cp >> 6);
        WtH[idx] = f2bf(Wh[(i << 18) + (e << 9) + c]);
        return;
    }
    int idx2 = idx - 3*512*512;
    if (idx2 >= 0 && idx2 < 512*512) {
        int c = idx2 >> 9; int ep = idx2 & 511;
        int row = ((ep & 63) << 3) | (ep >> 6);
        WtO[idx2] = f2bf(Wo[(row << 9) + c]);
        return;
    }
    int idx3 = idx2 - 512*512;
    if (idx3 >= 0 && idx3 < 3*512) {
        int i = idx3 >> 9; int cp = idx3 & 511;
        int c = ((cp & 63) << 3) | (cp >> 6);
        biasp[idx3] = bias[(i << 9) + c];
    }
}

// ---------------------------------------------------------------------------
// K1: FUSED cvt + projection GEMM (all 3 z, 2928 = 8*366).
// r10 structure (2 A reg sets, VGPR ~120, 2 blocks/CU) with ONE change:
// LOADA(kk+2) moved from after barrier-2 to right after barrier-1
// (ar[kk&1] holds A(kk), dead since its ds_write at end of iter kk-1).
// A(kk+1) issue->wait distance grows ~1.0 -> ~1.4 iterations at no VGPR
// cost. Ledger (in-order): top-of-iter vmcnt(12) retires B(kk) (kk<7);
// pre-DSWA vmcnt(16) retires A(kk+1) (kk<=5), vmcnt(4) at kk=6.
// ---------------------------------------------------------------------------
__global__ __launch_bounds__(256) void projf_gemm3(
    const float* __restrict__ A0, const float* __restrict__ A1, const float* __restrict__ A2,
    const unsigned short* __restrict__ Wt, const float* __restrict__ biasp,
    unsigned short* __restrict__ Y0, unsigned short* __restrict__ Y1, unsigned short* __restrict__ Y2)
{
    __shared__ __align__(16) unsigned short Sh[4*128*64];   // 64 KB

    int orig = blockIdx.x;
    int wg = (orig & 7) * 366 + (orig >> 3);   // bijective (2928 = 8*366)
    int z = wg / 976; int rem = wg - z * 976;
    int mtile = rem >> 2; int ntile = rem & 3;

    const float* Ap = (z == 0) ? A0 : ((z == 1) ? A1 : A2);
    unsigned short* Y = (z == 0) ? Y0 : ((z == 1) ? Y1 : Y2);
    const unsigned short* Btn = Wt + z * 512 * 512 + ntile * 128 * 512;
    const float* bias = biasp + z * 512;

    int t = threadIdx.x;
    int wid = t >> 6, lane = t & 63;
    int wm = wid >> 1, wn = wid & 1;
    int lm = lane & 15, lg = lane >> 4;

    long mbase = (long)mtile * 128;

    // A: fp32 16B-granule loads. granule G = i*256 + t; row=G>>4, col16=G&15.
    int tr = t >> 4, tc = t & 15;
    long aoffg[8];
    int awr[8];                     // u32x2 (8B) units into A half of a buffer
    #pragma unroll
    for (int i = 0; i < 8; ++i) {
        int rl = i * 16 + tr;
        long rg = mbase + rl; if (rg >= MROWS) rg = MROWS - 1;
        aoffg[i] = rg * 512 + tc * 4;
        awr[i] = rl * 16 + (((tc >> 1) ^ (rl & 7)) << 1) + (tc & 1);
    }
    // B: 16B granules, inverse-swizzled source, linear LDS dest
    int boff[4];
    #pragma unroll
    for (int r = 0; r < 4; ++r) {
        int G = ((r * 4 + wid) << 6) + lane;
        int row = G >> 3;
        int slot = (G & 7) ^ (row & 7);
        boff[r] = row * 512 + slot * 8;
    }

    f32x4 acc[4][4] = {};
    f32x4 ar[2][8];                 // ping-pong A reg tiles (compile-time indices)

#define LOADA(kk, S) { const int k0 = (kk) * 64;                               \
    _Pragma("unroll") for (int i = 0; i < 8; ++i)                              \
        ar[S][i] = *(const f32x4*)(Ap + aoffg[i] + k0); }
#define STAGEB(kk, b) { unsigned short* Bs_ = Sh + (b) * 16384 + 8192;         \
    const int k0 = (kk) * 64;                                                  \
    _Pragma("unroll") for (int r = 0; r < 4; ++r)                              \
        gload16(Btn + boff[r] + k0, &Bs_[(r * 4 + wid) << 9]); }
#define DSWA(S, b) { u32x2* dst_ = (u32x2*)(Sh + (b) * 16384);                 \
    _Pragma("unroll") for (int i = 0; i < 8; ++i) {                            \
        u32x2 w_; w_[0] = cvt2(ar[S][i][0], ar[S][i][1]);                      \
        w_[1] = cvt2(ar[S][i][2], ar[S][i][3]); dst_[awr[i]] = w_; } }

    // prologue: A0->regs, B0->buf0, write A0; A1->regs, B1->buf1
    LOADA(0, 0); MEMFENCE;
    STAGEB(0, 0); MEMFENCE;
    asm volatile("s_waitcnt vmcnt(4)" ::: "memory");     // A0 regs done (B0 in flight)
    DSWA(0, 0);
    LOADA(1, 1); MEMFENCE;
    STAGEB(1, 1); MEMFENCE;

    #pragma unroll
    for (int kk = 0; kk < 8; ++kk) {
        const int b = kk & 1;
        // retire B(kk); A(kk+1) (older) rides along where applicable
        if (kk < 7) asm volatile("s_waitcnt vmcnt(12)" ::: "memory");
        else        asm volatile("s_waitcnt vmcnt(0)"  ::: "memory");
        asm volatile("s_waitcnt lgkmcnt(0)" ::: "memory");   // A ds_writes visible
        __builtin_amdgcn_s_barrier();

        // issue A(kk+2) EARLY: ar[kk&1] (held A(kk)) is dead since its
        // ds_write completed at the end of iter kk-1.
        if (kk <= 5) { LOADA(kk + 2, b); MEMFENCE; }

        const unsigned short* As = Sh + b * 16384;
        const unsigned short* Bs = As + 8192;
        #pragma unroll
        for (int ks = 0; ks < 2; ++ks) {
            s16x8 afr[4], bfr[4];
            #pragma unroll
            for (int mf = 0; mf < 4; ++mf) {
                int row = wm * 64 + mf * 16 + lm;
                afr[mf] = ((const s16x8*)As)[row * 8 + ((ks * 4 + lg) ^ (row & 7))];
            }
            #pragma unroll
            for (int nf = 0; nf < 4; ++nf) {
                int row = wn * 64 + nf * 16 + lm;
                bfr[nf] = ((const s16x8*)Bs)[row * 8 + ((ks * 4 + lg) ^ (row & 7))];
            }
            #pragma unroll
            for (int mf = 0; mf < 4; ++mf)
                #pragma unroll
                for (int nf = 0; nf < 4; ++nf)
                    acc[mf][nf] = __builtin_amdgcn_mfma_f32_16x16x32_bf16(afr[mf], bfr[nf], acc[mf][nf], 0, 0, 0);
        }
        MEMFENCE;
        __builtin_amdgcn_s_barrier();           // buffer b free
        if (kk <= 5) { STAGEB(kk + 2, b); MEMFENCE; }
        if (kk <= 6) {
            if (kk <= 5) asm volatile("s_waitcnt vmcnt(16)" ::: "memory");  // A(kk+1) done
            else         asm volatile("s_waitcnt vmcnt(4)"  ::: "memory");
            DSWA((kk + 1) & 1, b ^ 1);          // write A(kk+1) into buf b^1
        }
    }
#undef LOADA
#undef STAGEB
#undef DSWA

    // ---- LDS-transpose epilogue (Sh[0..32KB) as 128x128 bf16) ----
    __syncthreads();
    #pragma unroll
    for (int nf = 0; nf < 4; ++nf) {
        int col = wn * 64 + nf * 16 + lm;
        float bv = bias[ntile * 128 + col];
        #pragma unroll
        for (int mf = 0; mf < 4; ++mf) {
            #pragma unroll
            for (int j = 0; j < 4; ++j) {
                int row = wm * 64 + mf * 16 + lg * 4 + j;
                Sh[row * 128 + (col ^ ((row & 12) << 2))] = bf1(acc[mf][nf][j] + bv);
            }
        }
    }
    __syncthreads();
    #pragma unroll
    for (int it = 0; it < 8; ++it) {
        int row = it * 16 + (t >> 4);
        int c8 = (t & 15) * 8;
        u32x4 v = *(const u32x4*)&Sh[row * 128 + (c8 ^ ((row & 12) << 2))];
        long grow = mbase + row;
        if (grow < MROWS)
            *(u32x4*)&Y[grow * 512 + ntile * 128 + c8] = v;
    }
}

// ---------------------------------------------------------------------------
// K3: out-projection + residual, counted-vmcnt pipelined GEMM.
// ---------------------------------------------------------------------------
__global__ __launch_bounds__(256) void out_gemm(
    const unsigned short* __restrict__ A, const unsigned short* __restrict__ Bt,
    const float* __restrict__ X, unsigned short* __restrict__ Out)
{
    __shared__ __align__(16) unsigned short Sh[4*128*64];

    int orig = blockIdx.x;
    int wg = (orig & 7) * 122 + (orig >> 3);
    int mtile = wg >> 2; int ntile = wg & 3;

    int t = threadIdx.x;
    int wid = t >> 6, lane = t & 63;
    int wm = wid >> 1, wn = wid & 1;
    int lm = lane & 15, lg = lane >> 4;

    long mbase = (long)mtile * 128;
    const unsigned short* Abase = A + mbase * 512;
    const unsigned short* Btn = Bt + ntile * 128 * 512;

    int aoff[4], boff[4];
    #pragma unroll
    for (int r = 0; r < 4; ++r) {
        int G = ((r * 4 + wid) << 6) + lane;
        int row = G >> 3;
        int slot = (G & 7) ^ (row & 7);
        int rowc = row;
        if (mbase + row > MROWS - 1) rowc = (int)(MROWS - 1 - mbase);
        aoff[r] = rowc * 512 + slot * 8;
        boff[r] = row * 512 + slot * 8;
    }

    f32x4 acc[4][4] = {};

    auto STAGE = [&](int kk, int b) {
        unsigned short* As = Sh + b * 16384;
        unsigned short* Bs = As + 8192;
        const int k0 = kk * 64;
        #pragma unroll
        for (int r = 0; r < 4; ++r)
            gload16(Abase + aoff[r] + k0, &As[(r * 4 + wid) << 9]);
        #pragma unroll
        for (int r = 0; r < 4; ++r)
            gload16(Btn + boff[r] + k0, &Bs[(r * 4 + wid) << 9]);
    };

    STAGE(0, 0);
    STAGE(1, 1);

    #pragma unroll
    for (int kk = 0; kk < 8; ++kk) {
        const int b = kk & 1;
        if (kk < 7) asm volatile("s_waitcnt vmcnt(8)" ::: "memory");
        else        asm volatile("s_waitcnt vmcnt(0)" ::: "memory");
        __builtin_amdgcn_s_barrier();

        const unsigned short* As = Sh + b * 16384;
        const unsigned short* Bs = As + 8192;
        #pragma unroll
        for (int ks = 0; ks < 2; ++ks) {
            s16x8 afr[4], bfr[4];
            #pragma unroll
            for (int mf = 0; mf < 4; ++mf) {
                int row = wm * 64 + mf * 16 + lm;
                afr[mf] = ((const s16x8*)As)[row * 8 + ((ks * 4 + lg) ^ (row & 7))];
            }
            #pragma unroll
            for (int nf = 0; nf < 4; ++nf) {
                int row = wn * 64 + nf * 16 + lm;
                bfr[nf] = ((const s16x8*)Bs)[row * 8 + ((ks * 4 + lg) ^ (row & 7))];
            }
            #pragma unroll
            for (int mf = 0; mf < 4; ++mf)
                #pragma unroll
                for (int nf = 0; nf < 4; ++nf)
                    acc[mf][nf] = __builtin_amdgcn_mfma_f32_16x16x32_bf16(afr[mf], bfr[nf], acc[mf][nf], 0, 0, 0);
        }
        MEMFENCE;
        __builtin_amdgcn_s_barrier();
        if (kk + 2 < 8) STAGE(kk + 2, b);
    }

    __syncthreads();
    #pragma unroll
    for (int nf = 0; nf < 4; ++nf) {
        int col = wn * 64 + nf * 16 + lm;
        #pragma unroll
        for (int mf = 0; mf < 4; ++mf) {
            #pragma unroll
            for (int j = 0; j < 4; ++j) {
                int row = wm * 64 + mf * 16 + lg * 4 + j;
                Sh[row * 128 + (col ^ ((row & 12) << 2))] = bf1(acc[mf][nf][j]);
            }
        }
    }
    __syncthreads();
    #pragma unroll
    for (int it = 0; it < 8; ++it) {
        int row = it * 16 + (t >> 4);
        int c8 = (t & 15) * 8;
        u32x4 v = *(const u32x4*)&Sh[row * 128 + (c8 ^ ((row & 12) << 2))];
        long grow = mbase + row;
        if (grow < MROWS) {
            long gidx = grow * 512 + ntile * 128 + c8;
            const float* xp = X + gidx;
            f32x4 x0 = *(const f32x4*)xp, x1 = *(const f32x4*)(xp + 4);
            float xx[8] = {x0[0], x0[1], x0[2], x0[3], x1[0], x1[1], x1[2], x1[3]};
            u32x4 o;
            #pragma unroll
            for (int q = 0; q < 4; ++q) {
                float lo = bf2f(v[q] & 0xffffu) + xx[2 * q];
                float hi = bf2f(v[q] >> 16)     + xx[2 * q + 1];
                o[q] = cvt2(lo, hi);
            }
            *(u32x4*)&Out[gidx] = o;
        }
    }
}

// ---------------------------------------------------------------------------
// K2: attention, QBLK=128, shift-free softmax (unchanged).
// ---------------------------------------------------------------------------
#define SCALE2 0.18033688f   // 0.125 * log2(e)

__global__ __launch_bounds__(256) void attn_kernel(
    const unsigned short* __restrict__ Qw, const unsigned short* __restrict__ Kw,
    const unsigned short* __restrict__ Vw, unsigned short* __restrict__ Ow)
{
    __shared__ __align__(16) unsigned short Qs[128*64];
    __shared__ __align__(16) unsigned short Ks[64*64];
    __shared__ __align__(16) unsigned short Vts[64*64];
    __shared__ __align__(16) unsigned short Ps[4][16*64];

    int bid = blockIdx.x;
    int x = bid & 7, s = bid >> 3;
    int qc = s % 3;
    int gi = s / 3;
    int g  = x + 8 * gi;
    int h  = g & 7, bt = g >> 3;

    int t = threadIdx.x;
    int wid = t >> 6, lane = t & 63, lm = lane & 15, lg = lane >> 4;

    long rowbase = (long)bt * NN;
    int colbase = h * 64;
    int q0 = qc * 128;

    {
        int i = t >> 1, half = t & 1;
        int rowc = q0 + i; if (rowc > NN - 1) rowc = NN - 1;
        const u32x4* src = (const u32x4*)(Qw + (rowbase + rowc) * 512 + colbase);
        u32x4* dst = (u32x4*)Qs;
        #pragma unroll
        for (int ss = 0; ss < 4; ++ss) {
            int slot = half * 4 + ss;
            dst[i * 8 + (slot ^ (i & 7))] = src[slot];
        }
    }
    __syncthreads();
    s16x8 aq[2][2];
    #pragma unroll
    for (int qs = 0; qs < 2; ++qs) {
        int row = qs * 64 + wid * 16 + lm;
        aq[qs][0] = ((const s16x8*)Qs)[row * 8 + ((0 + lg) ^ (row & 7))];
        aq[qs][1] = ((const s16x8*)Qs)[row * 8 + ((4 + lg) ^ (row & 7))];
    }

    f32x4 oacc[2][4] = {};
    float lsum[2][4] = {};

    for (int tile = 0; tile < 6; ++tile) {
        const int kv0 = tile * 64;
        __syncthreads();
        #pragma unroll
        for (int r = 0; r < 2; ++r) {
            int G = r * 256 + t;
            int row = G >> 3;
            int slot = (G & 7) ^ (row & 7);
            int rowg = kv0 + row; if (rowg > NN - 1) rowg = NN - 1;
            gload16(Kw + (rowbase + rowg) * 512 + colbase + slot * 8, &Ks[G * 8]);
        }
        {
            int i = t >> 2, quarter = t & 3;
            int rowc = kv0 + i; if (rowc > NN - 1) rowc = NN - 1;
            const u32x4* src = (const u32x4*)(Vw + (rowbase + rowc) * 512 + colbase + quarter * 16);
            unsigned short vb[16] __attribute__((aligned(16)));
            *((u32x4*)vb) = src[0];
            *((u32x4*)(vb + 8)) = src[1];
            #pragma unroll
            for (int e = 0; e < 16; ++e) {
                int dk = quarter * 16 + e;
                int sv = (dk & 7) ^ ((dk >> 3) & 7);
                Vts[dk * 64 + (i ^ (sv << 3))] = vb[e];
            }
        }
        asm volatile("s_waitcnt vmcnt(0)" ::: "memory");
        __syncthreads();

        const bool tail = (tile == 5);
        #pragma unroll
        for (int qs = 0; qs < 2; ++qs) {
            f32x4 sacc[4] = {};
            #pragma unroll
            for (int ks = 0; ks < 2; ++ks) {
                #pragma unroll
                for (int nf = 0; nf < 4; ++nf) {
                    int row = nf * 16 + lm;
                    s16x8 bk = ((const s16x8*)Ks)[row * 8 + ((ks*4 + lg) ^ (row & 7))];
                    sacc[nf] = __builtin_amdgcn_mfma_f32_16x16x32_bf16(aq[qs][ks], bk, sacc[nf], 0, 0, 0);
                }
            }
            #pragma unroll
            for (int nf = 0; nf < 4; ++nf) {
                bool valid = !tail || (kv0 + nf * 16 + lm < NN);
                #pragma unroll
                for (int j = 0; j < 4; ++j) {
                    float pv = valid ? exp2f(sacc[nf][j] * SCALE2) : 0.f;
                    lsum[qs][j] += pv;
                    int r = lg * 4 + j;
                    int col = nf * 16 + lm;
                    Ps[wid][r * 64 + (col ^ (((r >> 1) & 7) << 3))] = bf1(pv);
                }
            }
            #pragma unroll
            for (int ks = 0; ks < 2; ++ks) {
                s16x8 ap = ((const s16x8*)Ps[wid])[lm * 8 + ((ks*4 + lg) ^ ((lm >> 1) & 7))];
                #pragma unroll
                for (int df = 0; df < 4; ++df) {
                    int vrow = df * 16 + lm;
                    int sv = (vrow & 7) ^ ((vrow >> 3) & 7);
                    s16x8 bv = ((const s16x8*)Vts)[vrow * 8 + ((ks*4 + lg) ^ sv)];
                    oacc[qs][df] = __builtin_amdgcn_mfma_f32_16x16x32_bf16(ap, bv, oacc[qs][df], 0, 0, 0);
                }
            }
        }
    }

    #pragma unroll
    for (int qs = 0; qs < 2; ++qs) {
        float inv[4];
        #pragma unroll
        for (int j = 0; j < 4; ++j) {
            float v = lsum[qs][j];
            v += __shfl_xor(v, 1, 16);
            v += __shfl_xor(v, 2, 16);
            v += __shfl_xor(v, 4, 16);
            v += __shfl_xor(v, 8, 16);
            inv[j] = __builtin_amdgcn_rcpf(v);
        }
        #pragma unroll
        for (int df = 0; df < 4; ++df) {
            int dk = df * 16 + lm;
            #pragma unroll
            for (int j = 0; j < 4; ++j) {
                int rloc = q0 + qs * 64 + wid * 16 + lg * 4 + j;
                if (rloc < NN)
                    Ow[(rowbase + rloc) * 512 + colbase + dk] = bf1(oacc[qs][df][j] * inv[j]);
            }
        }
    }
}

// ---------------------------------------------------------------------------
// K4: LayerNorm over D=512 (bf16 input, fp32 output), one wave per row.
// ---------------------------------------------------------------------------
__global__ __launch_bounds__(256) void ln_kernel(
    const unsigned short* __restrict__ T, const float* __restrict__ gamma,
    const float* __restrict__ beta, float* __restrict__ Outp)
{
    int wid = threadIdx.x >> 6, lane = threadIdx.x & 63;
    long row = (long)blockIdx.x * 4 + wid;
    s16x8 h = ((const s16x8*)(T + row * 512))[lane];
    float v[8];
    #pragma unroll
    for (int j = 0; j < 8; ++j) v[j] = bf2f((unsigned int)(unsigned short)h[j]);
    float s = 0.f, sq = 0.f;
    #pragma unroll
    for (int j = 0; j < 8; ++j) { s += v[j]; sq += v[j] * v[j]; }
    #pragma unroll
    for (int m = 1; m < 64; m <<= 1) {
        s  += __shfl_xor(s, m);
        sq += __shfl_xor(sq, m);
    }
    float mean = s * (1.f / 512.f);
    float var = sq * (1.f / 512.f) - mean * mean;
    float rstd = rsqrtf(var + 1e-5f);
    const float4* g = (const float4*)gamma;
    const float4* b = (const float4*)beta;
    float4 g0 = g[lane * 2], g1 = g[lane * 2 + 1];
    float4 b0 = b[lane * 2], b1 = b[lane * 2 + 1];
    float4 o0, o1;
    o0.x = (v[0] - mean) * rstd * g0.x + b0.x;
    o0.y = (v[1] - mean) * rstd * g0.y + b0.y;
    o0.z = (v[2] - mean) * rstd * g0.z + b0.z;
    o0.w = (v[3] - mean) * rstd * g0.w + b0.w;
    o1.x = (v[4] - mean) * rstd * g1.x + b1.x;
    o1.y = (v[5] - mean) * rstd * g1.y + b1.y;
    o1.z = (v[6] - mean) * rstd * g1.z + b1.z;
    o1.w = (v[7] - mean) * rstd * g1.w + b1.w;
    float4* dst = (float4*)(Outp + row * 512);
    dst[lane * 2]     = o0;
    dst[lane * 2 + 1] = o1;
}

// ---------------------------------------------------------------------------
extern "C" void kernel_launch(void* const* d_in, const int* in_sizes, int n_in,
                              void* d_out, int out_size, void* d_ws, size_t ws_size,
                              hipStream_t stream)
{
    const float* X  = (const float*)d_in[0];
    const float* Q  = (const float*)d_in[1];
    const float* K  = (const float*)d_in[2];
    const float* V  = (const float*)d_in[3];
    const float* Wh = (const float*)d_in[4];
    const float* bi = (const float*)d_in[5];
    const float* Wo = (const float*)d_in[6];
    const float* gamma = (const float*)d_in[7];
    const float* beta  = (const float*)d_in[8];

    char* ws = (char*)d_ws;
    const size_t msz = (size_t)MROWS * 512 * 2;          // ~31.9 MB
    unsigned short* q_ws = (unsigned short*)(ws);
    unsigned short* k_ws = (unsigned short*)(ws + msz);
    unsigned short* v_ws = (unsigned short*)(ws + 2 * msz);
    unsigned short* o_ws = (unsigned short*)(ws + 3 * msz);
    unsigned short* WtH  = (unsigned short*)(ws + 4 * msz);
    unsigned short* WtO  = WtH + 3 * 512 * 512;
    float* biasp         = (float*)(ws + 4 * msz + (size_t)4*512*512*2);
    unsigned short* tmpb = q_ws;   // pre-LN bf16; q dead after attention

    prep_kernel<<<4102, 256, 0, stream>>>(Wh, bi, Wo, WtH, WtO, biasp);

    projf_gemm3<<<2928, 256, 0, stream>>>(Q, K, V, WtH, biasp, q_ws, k_ws, v_ws);

    attn_kernel<<<2304, 256, 0, stream>>>(q_ws, k_ws, v_ws, o_ws);

    out_gemm<<<976, 256, 0, stream>>>(o_ws, WtO, X, tmpb);

    ln_kernel<<<7800, 256, 0, stream>>>(tmpb, gamma, beta, (float*)d_out);
}